// Round 1
// baseline (623.908 us; speedup 1.0000x reference)
//
#include <hip/hip_runtime.h>

#define B_    128
#define L_    512
#define H_    256
#define TGB_  128
#define S_    1023
#define BL_   (B_ * L_)     // 65536
#define SIXH  1536
#define FOURH 1024

typedef __bf16 bf16_t;
typedef bf16_t bf16x8 __attribute__((ext_vector_type(8)));
typedef float  f32x4  __attribute__((ext_vector_type(4)));

__device__ __forceinline__ unsigned short f2bf(float f) {
    union { float f; unsigned u; } v; v.f = f;
    unsigned u = v.u;
    unsigned r = u + 0x7FFFu + ((u >> 16) & 1u);   // round-to-nearest-even
    return (unsigned short)(r >> 16);
}
__device__ __forceinline__ float bf2f(unsigned short s) {
    union { unsigned u; float f; } v; v.u = ((unsigned)s) << 16;
    return v.f;
}

__device__ __forceinline__ void gload_lds16(const void* g, void* l) {
    __builtin_amdgcn_global_load_lds(
        (__attribute__((address_space(1))) void*)(void*)(g),
        (__attribute__((address_space(3))) void*)(l), 16, 0, 0);
}

// ---------------------------------------------------------------------------
// K0: transpose + f32->bf16 convert:  in (R x C) f32  ->  out (C x R) bf16
// ---------------------------------------------------------------------------
__global__ __launch_bounds__(256) void transpose_bf16_kernel(
    const float* __restrict__ in, unsigned short* __restrict__ out,
    int R, int C)
{
    __shared__ float tile[32][33];
    int rb = blockIdx.x * 32, cb = blockIdx.y * 32;
    int tx = threadIdx.x & 31, ty = threadIdx.x >> 5;   // 32 x 8
    #pragma unroll
    for (int d = 0; d < 32; d += 8)
        tile[ty + d][tx] = in[(size_t)(rb + ty + d) * C + cb + tx];
    __syncthreads();
    #pragma unroll
    for (int d = 0; d < 32; d += 8)
        out[(size_t)(cb + ty + d) * R + rb + tx] = f2bf(tile[tx][ty + d]);
}

// ---------------------------------------------------------------------------
// K1: gather 6 embeddings + LayerNorm over 1536 -> x_ln bf16 (BL x 1536)
// one block per event, 256 threads (thread t owns lane t of each 256-chunk)
// ---------------------------------------------------------------------------
__global__ __launch_bounds__(256) void embed_ln_kernel(
    const int* __restrict__ tok,  const int* __restrict__ ptok,
    const int* __restrict__ atok, const int* __restrict__ actok,
    const int* __restrict__ tgap, const int* __restrict__ gid,
    const float* __restrict__ ttab, const float* __restrict__ titab,
    const float* __restrict__ gtab, const float* __restrict__ gamma,
    const float* __restrict__ beta, unsigned short* __restrict__ xln)
{
    int e = blockIdx.x;
    int t = threadIdx.x;
    int i0 = tok[e], i1 = ptok[e], i2 = atok[e], i3 = actok[e];
    int i4 = tgap[e]; i4 = i4 < 0 ? 0 : (i4 > TGB_ ? TGB_ : i4);
    int i5 = gid[e];
    float v0 = ttab[(size_t)i0 * H_ + t];
    float v1 = ttab[(size_t)i1 * H_ + t];
    float v2 = ttab[(size_t)i2 * H_ + t];
    float v3 = ttab[(size_t)i3 * H_ + t];
    float v4 = titab[(size_t)i4 * H_ + t];
    float v5 = gtab[(size_t)i5 * H_ + t];
    float s  = v0 + v1 + v2 + v3 + v4 + v5;
    float sq = v0*v0 + v1*v1 + v2*v2 + v3*v3 + v4*v4 + v5*v5;
    #pragma unroll
    for (int off = 32; off > 0; off >>= 1) {
        s  += __shfl_down(s,  off);
        sq += __shfl_down(sq, off);
    }
    __shared__ float red[8];
    int lane = t & 63, w = t >> 6;
    if (lane == 0) { red[w] = s; red[4 + w] = sq; }
    __syncthreads();
    float stot  = red[0] + red[1] + red[2] + red[3];
    float sqtot = red[4] + red[5] + red[6] + red[7];
    float mean = stot * (1.0f / 1536.0f);
    float var  = sqtot * (1.0f / 1536.0f) - mean * mean;
    float rstd = rsqrtf(var + 1e-5f);
    float vv[6] = { v0, v1, v2, v3, v4, v5 };
    unsigned short* orow = xln + (size_t)e * SIXH;
    #pragma unroll
    for (int k = 0; k < 6; ++k) {
        int idx = k * H_ + t;
        float y = (vv[k] - mean) * rstd * gamma[idx] + beta[idx];
        orow[idx] = f2bf(y);
    }
}

// ---------------------------------------------------------------------------
// K2: bf16 MFMA GEMM, C(MxN) = epi(A(MxK) @ Bt(NxK)^T + bias)
// 128x128 tile, BK=32, 256 threads = 4 waves (2x2), 16x16x32 MFMA,
// global_load_lds width 16 (m97 structure)
// EPI 0: silu   EPI 1: plain bias add
// ---------------------------------------------------------------------------
template<int N, int K, int EPI>
__global__ __launch_bounds__(256) void gemm_kernel(
    const unsigned short* __restrict__ A,
    const unsigned short* __restrict__ Bt,
    const float* __restrict__ bias,
    unsigned short* __restrict__ C)
{
    static_assert(K % 32 == 0 && N % 128 == 0, "tile divisibility");
    __shared__ __align__(16) unsigned short sA[128 * 32];
    __shared__ __align__(16) unsigned short sB[128 * 32];
    int m0 = blockIdx.x * 128;
    int n0 = blockIdx.y * 128;
    int t = threadIdx.x;
    int lane = t & 63, w = t >> 6;
    int wm = w >> 1, wn = w & 1;
    int r = lane & 15, q = lane >> 4;

    f32x4 acc[4][4];
    #pragma unroll
    for (int i = 0; i < 4; ++i)
        #pragma unroll
        for (int j = 0; j < 4; ++j) acc[i][j] = (f32x4)0.0f;

    int srow = t >> 2;            // 0..63
    int scol = (t & 3) * 8;       // 0,8,16,24
    const unsigned short* Abase = A  + (size_t)(m0 + srow) * K + scol;
    const unsigned short* Bbase = Bt + (size_t)(n0 + srow) * K + scol;

    for (int kt = 0; kt < K / 32; ++kt) {
        __syncthreads();
        const unsigned short* Ak = Abase + kt * 32;
        const unsigned short* Bk = Bbase + kt * 32;
        gload_lds16(Ak,                 sA + w * 512);           // rows 0..63
        gload_lds16(Ak + (size_t)64 * K, sA + 2048 + w * 512);    // rows 64..127
        gload_lds16(Bk,                 sB + w * 512);
        gload_lds16(Bk + (size_t)64 * K, sB + 2048 + w * 512);
        __syncthreads();

        bf16x8 af[4], bfr[4];
        #pragma unroll
        for (int mi = 0; mi < 4; ++mi)
            af[mi] = *(const bf16x8*)(sA + ((wm * 64 + mi * 16 + r) * 32 + q * 8));
        #pragma unroll
        for (int ni = 0; ni < 4; ++ni)
            bfr[ni] = *(const bf16x8*)(sB + ((wn * 64 + ni * 16 + r) * 32 + q * 8));
        #pragma unroll
        for (int mi = 0; mi < 4; ++mi)
            #pragma unroll
            for (int ni = 0; ni < 4; ++ni)
                acc[mi][ni] = __builtin_amdgcn_mfma_f32_16x16x32_bf16(
                    af[mi], bfr[ni], acc[mi][ni], 0, 0, 0);
    }

    #pragma unroll
    for (int mi = 0; mi < 4; ++mi) {
        #pragma unroll
        for (int ni = 0; ni < 4; ++ni) {
            int col = n0 + wn * 64 + ni * 16 + r;
            float bv = bias[col];
            #pragma unroll
            for (int j = 0; j < 4; ++j) {
                int row = m0 + wm * 64 + mi * 16 + q * 4 + j;
                float v = acc[mi][ni][j] + bv;
                if (EPI == 0) v = v / (1.0f + __expf(-v));   // silu
                C[(size_t)row * N + col] = f2bf(v);
            }
        }
    }
}

// ---------------------------------------------------------------------------
// K3: per-batch boundary + exclusive cumsum + inverse index map
// idx_map[b][s]: >=0 event index, -2 sep, -1 empty
// ---------------------------------------------------------------------------
__global__ __launch_bounds__(512) void scan_scatter_kernel(
    const int* __restrict__ gid, const int* __restrict__ lengths,
    int* __restrict__ idx_map, int* __restrict__ shiftb)
{
    int b = blockIdx.x, i = threadIdx.x;
    int len = lengths[b];
    int g  = gid[b * L_ + i];
    int gn = (i < L_ - 1) ? gid[b * L_ + i + 1] : g;
    int bnd = (i < len - 1 && g != gn) ? 1 : 0;
    __shared__ int sc[512];
    sc[i] = bnd;
    __syncthreads();
    for (int off = 1; off < 512; off <<= 1) {
        int v = (i >= off) ? sc[i - off] : 0;
        __syncthreads();
        sc[i] += v;
        __syncthreads();
    }
    int incl  = sc[i];
    int total = sc[511];
    int ex = incl - bnd;
    int M = len + total;
    int shift = S_ - M;          // always >= 0
    for (int s = i; s < S_; s += 512) idx_map[b * S_ + s] = -1;
    __syncthreads();
    if (i < len) {
        int p = shift + i + ex;
        idx_map[b * S_ + p] = i;
        if (bnd) idx_map[b * S_ + p + 1] = -2;
    }
    if (i == 0) shiftb[b] = shift;
}

// ---------------------------------------------------------------------------
// K4: final fill: merged[b][s][:] and mask[b][s]
// ---------------------------------------------------------------------------
__global__ __launch_bounds__(256) void out_kernel(
    const int* __restrict__ idx_map, const int* __restrict__ shiftb,
    const unsigned short* __restrict__ event,
    const float* __restrict__ pos_table, const float* __restrict__ sep,
    float* __restrict__ out)
{
    int s = blockIdx.x, b = blockIdx.y, t = threadIdx.x;
    int shift = shiftb[b];
    float val = 0.0f;
    if (s >= shift) {
        int idx = idx_map[b * S_ + s];
        float add = 0.0f;
        if (idx >= 0)       add = bf2f(event[((size_t)b * L_ + idx) * H_ + t]);
        else if (idx == -2) add = sep[t];
        val = pos_table[(size_t)s * H_ + t] + add;
    }
    out[((size_t)b * S_ + s) * H_ + t] = val;
    if (t == 0)
        out[(size_t)B_ * S_ * H_ + (size_t)b * S_ + s] = (s >= shift) ? 1.0f : 0.0f;
}

// ---------------------------------------------------------------------------
extern "C" void kernel_launch(void* const* d_in, const int* in_sizes, int n_in,
                              void* d_out, int out_size, void* d_ws, size_t ws_size,
                              hipStream_t stream)
{
    const int*   tok   = (const int*)d_in[0];
    const int*   ptok  = (const int*)d_in[1];
    const int*   atok  = (const int*)d_in[2];
    const int*   actok = (const int*)d_in[3];
    const int*   tgap  = (const int*)d_in[4];
    const int*   gid   = (const int*)d_in[5];
    const int*   lens  = (const int*)d_in[6];
    const float* ttab  = (const float*)d_in[7];
    const float* titab = (const float*)d_in[8];
    const float* gtab  = (const float*)d_in[9];
    const float* post  = (const float*)d_in[10];
    const float* sep   = (const float*)d_in[11];
    const float* gamma = (const float*)d_in[12];
    const float* beta  = (const float*)d_in[13];
    const float* W1    = (const float*)d_in[14];
    const float* b1    = (const float*)d_in[15];
    const float* W2    = (const float*)d_in[16];
    const float* b2    = (const float*)d_in[17];

    unsigned short* xln  = (unsigned short*)d_ws;                 // BL*1536 bf16
    unsigned short* hbuf = xln  + (size_t)BL_ * SIXH;             // BL*1024 bf16
    unsigned short* evb  = hbuf + (size_t)BL_ * FOURH;            // BL*256  bf16
    unsigned short* W1T  = evb  + (size_t)BL_ * H_;               // 1024*1536 bf16
    unsigned short* W2T  = W1T  + (size_t)FOURH * SIXH;           // 256*1024 bf16
    int* idx_map = (int*)(W2T + (size_t)H_ * FOURH);              // B*S int
    int* shiftb  = idx_map + B_ * S_;                             // B int
    float* out   = (float*)d_out;

    // weight transposes (f32 -> bf16, NxK layout for MFMA B-operand)
    transpose_bf16_kernel<<<dim3(SIXH / 32, FOURH / 32), 256, 0, stream>>>(W1, W1T, SIXH, FOURH);
    transpose_bf16_kernel<<<dim3(FOURH / 32, H_ / 32),   256, 0, stream>>>(W2, W2T, FOURH, H_);

    // embed + layernorm
    embed_ln_kernel<<<BL_, 256, 0, stream>>>(tok, ptok, atok, actok, tgap, gid,
                                             ttab, titab, gtab, gamma, beta, xln);

    // MLP
    gemm_kernel<FOURH, SIXH, 0><<<dim3(BL_ / 128, FOURH / 128), 256, 0, stream>>>(xln, W1T, b1, hbuf);
    gemm_kernel<H_, FOURH, 1><<<dim3(BL_ / 128, H_ / 128),      256, 0, stream>>>(hbuf, W2T, b2, evb);

    // scan + inverse scatter map
    scan_scatter_kernel<<<B_, 512, 0, stream>>>(gid, lens, idx_map, shiftb);

    // final output
    out_kernel<<<dim3(S_, B_), 256, 0, stream>>>(idx_map, shiftb, evb, post, sep, out);
}

// Round 2
// 583.279 us; speedup vs baseline: 1.0697x; 1.0697x over previous
//
#include <hip/hip_runtime.h>

#define B_    128
#define L_    512
#define H_    256
#define TGB_  128
#define S_    1023
#define BL_   (B_ * L_)     // 65536
#define SIXH  1536
#define FOURH 1024

typedef __bf16 bf16_t;
typedef bf16_t bf16x8 __attribute__((ext_vector_type(8)));
typedef float  f32x4  __attribute__((ext_vector_type(4)));

__device__ __forceinline__ unsigned short f2bf(float f) {
    union { float f; unsigned u; } v; v.f = f;
    unsigned u = v.u;
    unsigned r = u + 0x7FFFu + ((u >> 16) & 1u);   // round-to-nearest-even
    return (unsigned short)(r >> 16);
}
__device__ __forceinline__ float bf2f(unsigned short s) {
    union { unsigned u; float f; } v; v.u = ((unsigned)s) << 16;
    return v.f;
}

__device__ __forceinline__ void gload_lds16(const void* g, void* l) {
    __builtin_amdgcn_global_load_lds(
        (__attribute__((address_space(1))) void*)(void*)(g),
        (__attribute__((address_space(3))) void*)(l), 16, 0, 0);
}

// ---------------------------------------------------------------------------
// K0: transpose + f32->bf16 convert:  in (R x C) f32  ->  out (C x R) bf16
// ---------------------------------------------------------------------------
__global__ __launch_bounds__(256) void transpose_bf16_kernel(
    const float* __restrict__ in, unsigned short* __restrict__ out,
    int R, int C)
{
    __shared__ float tile[32][33];
    int rb = blockIdx.x * 32, cb = blockIdx.y * 32;
    int tx = threadIdx.x & 31, ty = threadIdx.x >> 5;   // 32 x 8
    #pragma unroll
    for (int d = 0; d < 32; d += 8)
        tile[ty + d][tx] = in[(size_t)(rb + ty + d) * C + cb + tx];
    __syncthreads();
    #pragma unroll
    for (int d = 0; d < 32; d += 8)
        out[(size_t)(cb + ty + d) * R + rb + tx] = f2bf(tile[tx][ty + d]);
}

// ---------------------------------------------------------------------------
// K1: gather 6 embeddings + LayerNorm over 1536 -> x_ln bf16 (BL x 1536)
// ---------------------------------------------------------------------------
__global__ __launch_bounds__(256) void embed_ln_kernel(
    const int* __restrict__ tok,  const int* __restrict__ ptok,
    const int* __restrict__ atok, const int* __restrict__ actok,
    const int* __restrict__ tgap, const int* __restrict__ gid,
    const float* __restrict__ ttab, const float* __restrict__ titab,
    const float* __restrict__ gtab, const float* __restrict__ gamma,
    const float* __restrict__ beta, unsigned short* __restrict__ xln)
{
    int e = blockIdx.x;
    int t = threadIdx.x;
    int i0 = tok[e], i1 = ptok[e], i2 = atok[e], i3 = actok[e];
    int i4 = tgap[e]; i4 = i4 < 0 ? 0 : (i4 > TGB_ ? TGB_ : i4);
    int i5 = gid[e];
    float v0 = ttab[(size_t)i0 * H_ + t];
    float v1 = ttab[(size_t)i1 * H_ + t];
    float v2 = ttab[(size_t)i2 * H_ + t];
    float v3 = ttab[(size_t)i3 * H_ + t];
    float v4 = titab[(size_t)i4 * H_ + t];
    float v5 = gtab[(size_t)i5 * H_ + t];
    float s  = v0 + v1 + v2 + v3 + v4 + v5;
    float sq = v0*v0 + v1*v1 + v2*v2 + v3*v3 + v4*v4 + v5*v5;
    #pragma unroll
    for (int off = 32; off > 0; off >>= 1) {
        s  += __shfl_down(s,  off);
        sq += __shfl_down(sq, off);
    }
    __shared__ float red[8];
    int lane = t & 63, w = t >> 6;
    if (lane == 0) { red[w] = s; red[4 + w] = sq; }
    __syncthreads();
    float stot  = red[0] + red[1] + red[2] + red[3];
    float sqtot = red[4] + red[5] + red[6] + red[7];
    float mean = stot * (1.0f / 1536.0f);
    float var  = sqtot * (1.0f / 1536.0f) - mean * mean;
    float rstd = rsqrtf(var + 1e-5f);
    float vv[6] = { v0, v1, v2, v3, v4, v5 };
    unsigned short* orow = xln + (size_t)e * SIXH;
    #pragma unroll
    for (int k = 0; k < 6; ++k) {
        int idx = k * H_ + t;
        float y = (vv[k] - mean) * rstd * gamma[idx] + beta[idx];
        orow[idx] = f2bf(y);
    }
}

// ---------------------------------------------------------------------------
// K2: bf16 MFMA GEMM, C(MxN) = epi(A(MxK) @ Bt(NxK)^T + bias)
// 128x128 tile, BK=64, 256 threads = 4 waves (2x2), 16x16x32 MFMA.
// - n-fast work order + XCD-bijective swizzle: each XCD owns a contiguous
//   m-chunk; A streams once, B lives in per-XCD L2.
// - LDS rows are 128B: linear global_load_lds dest + inverse-XOR-swizzled
//   global source + XOR-swizzled ds_read (chunk ^= row&7) -> conflict-free.
// EPI 0: silu   EPI 1: plain bias add
// ---------------------------------------------------------------------------
template<int N, int K, int NT, int EPI>
__global__ __launch_bounds__(256) void gemm_kernel(
    const unsigned short* __restrict__ A,
    const unsigned short* __restrict__ Bt,
    const float* __restrict__ bias,
    unsigned short* __restrict__ C)
{
    static_assert(K % 64 == 0 && N == NT * 128, "tile divisibility");
    constexpr int CHUNK = 512 / 8 * NT;     // blocks per XCD (Mtiles=512)
    __shared__ __align__(16) unsigned short sA[128 * 64];
    __shared__ __align__(16) unsigned short sB[128 * 64];

    int bid = blockIdx.x;
    int wid = (bid & 7) * CHUNK + (bid >> 3);   // XCD-bijective swizzle
    int m0 = (wid / NT) * 128;
    int n0 = (wid % NT) * 128;

    int t = threadIdx.x;
    int lane = t & 63, w = t >> 6;
    int wm = w >> 1, wn = w & 1;
    int r = lane & 15, q = lane >> 4;

    f32x4 acc[4][4];
    #pragma unroll
    for (int i = 0; i < 4; ++i)
        #pragma unroll
        for (int j = 0; j < 4; ++j) acc[i][j] = (f32x4)0.0f;

    int srow   = t >> 3;    // 0..31 (row within 32-row staging slab)
    int schunk = t & 7;     // 16B chunk within 128B row

    for (int kt = 0; kt < K / 64; ++kt) {
        __syncthreads();
        #pragma unroll
        for (int j = 0; j < 4; ++j) {
            int row = j * 32 + srow;
            int cg  = schunk ^ (row & 7);    // inverse-swizzled source chunk
            gload_lds16(A  + (size_t)(m0 + row) * K + kt * 64 + cg * 8,
                        sA + j * 2048 + w * 512);
            gload_lds16(Bt + (size_t)(n0 + row) * K + kt * 64 + cg * 8,
                        sB + j * 2048 + w * 512);
        }
        __syncthreads();

        #pragma unroll
        for (int kk = 0; kk < 2; ++kk) {
            bf16x8 af[4], bfr[4];
            #pragma unroll
            for (int mi = 0; mi < 4; ++mi) {
                int row = wm * 64 + mi * 16 + r;
                int ch  = (q + kk * 4) ^ (r & 7);   // swizzled read chunk
                af[mi] = *(const bf16x8*)(sA + row * 64 + ch * 8);
            }
            #pragma unroll
            for (int ni = 0; ni < 4; ++ni) {
                int row = wn * 64 + ni * 16 + r;
                int ch  = (q + kk * 4) ^ (r & 7);
                bfr[ni] = *(const bf16x8*)(sB + row * 64 + ch * 8);
            }
            #pragma unroll
            for (int mi = 0; mi < 4; ++mi)
                #pragma unroll
                for (int ni = 0; ni < 4; ++ni)
                    acc[mi][ni] = __builtin_amdgcn_mfma_f32_16x16x32_bf16(
                        af[mi], bfr[ni], acc[mi][ni], 0, 0, 0);
        }
    }

    #pragma unroll
    for (int mi = 0; mi < 4; ++mi) {
        #pragma unroll
        for (int ni = 0; ni < 4; ++ni) {
            int col = n0 + wn * 64 + ni * 16 + r;
            float bv = bias[col];
            #pragma unroll
            for (int j = 0; j < 4; ++j) {
                int row = m0 + wm * 64 + mi * 16 + q * 4 + j;
                float v = acc[mi][ni][j] + bv;
                if (EPI == 0) v = v / (1.0f + __expf(-v));   // silu
                C[(size_t)row * N + col] = f2bf(v);
            }
        }
    }
}

// ---------------------------------------------------------------------------
// K3: per-batch boundary + exclusive cumsum + inverse index map
// ---------------------------------------------------------------------------
__global__ __launch_bounds__(512) void scan_scatter_kernel(
    const int* __restrict__ gid, const int* __restrict__ lengths,
    int* __restrict__ idx_map, int* __restrict__ shiftb)
{
    int b = blockIdx.x, i = threadIdx.x;
    int len = lengths[b];
    int g  = gid[b * L_ + i];
    int gn = (i < L_ - 1) ? gid[b * L_ + i + 1] : g;
    int bnd = (i < len - 1 && g != gn) ? 1 : 0;
    __shared__ int sc[512];
    sc[i] = bnd;
    __syncthreads();
    for (int off = 1; off < 512; off <<= 1) {
        int v = (i >= off) ? sc[i - off] : 0;
        __syncthreads();
        sc[i] += v;
        __syncthreads();
    }
    int incl  = sc[i];
    int total = sc[511];
    int ex = incl - bnd;
    int M = len + total;
    int shift = S_ - M;          // always >= 0
    for (int s = i; s < S_; s += 512) idx_map[b * S_ + s] = -1;
    __syncthreads();
    if (i < len) {
        int p = shift + i + ex;
        idx_map[b * S_ + p] = i;
        if (bnd) idx_map[b * S_ + p + 1] = -2;
    }
    if (i == 0) shiftb[b] = shift;
}

// ---------------------------------------------------------------------------
// K4: final fill: merged[b][s][:] and mask[b][s]
// ---------------------------------------------------------------------------
__global__ __launch_bounds__(256) void out_kernel(
    const int* __restrict__ idx_map, const int* __restrict__ shiftb,
    const unsigned short* __restrict__ event,
    const float* __restrict__ pos_table, const float* __restrict__ sep,
    float* __restrict__ out)
{
    int s = blockIdx.x, b = blockIdx.y, t = threadIdx.x;
    int shift = shiftb[b];
    float val = 0.0f;
    if (s >= shift) {
        int idx = idx_map[b * S_ + s];
        float add = 0.0f;
        if (idx >= 0)       add = bf2f(event[((size_t)b * L_ + idx) * H_ + t]);
        else if (idx == -2) add = sep[t];
        val = pos_table[(size_t)s * H_ + t] + add;
    }
    out[((size_t)b * S_ + s) * H_ + t] = val;
    if (t == 0)
        out[(size_t)B_ * S_ * H_ + (size_t)b * S_ + s] = (s >= shift) ? 1.0f : 0.0f;
}

// ---------------------------------------------------------------------------
extern "C" void kernel_launch(void* const* d_in, const int* in_sizes, int n_in,
                              void* d_out, int out_size, void* d_ws, size_t ws_size,
                              hipStream_t stream)
{
    const int*   tok   = (const int*)d_in[0];
    const int*   ptok  = (const int*)d_in[1];
    const int*   atok  = (const int*)d_in[2];
    const int*   actok = (const int*)d_in[3];
    const int*   tgap  = (const int*)d_in[4];
    const int*   gid   = (const int*)d_in[5];
    const int*   lens  = (const int*)d_in[6];
    const float* ttab  = (const float*)d_in[7];
    const float* titab = (const float*)d_in[8];
    const float* gtab  = (const float*)d_in[9];
    const float* post  = (const float*)d_in[10];
    const float* sep   = (const float*)d_in[11];
    const float* gamma = (const float*)d_in[12];
    const float* beta  = (const float*)d_in[13];
    const float* W1    = (const float*)d_in[14];
    const float* b1    = (const float*)d_in[15];
    const float* W2    = (const float*)d_in[16];
    const float* b2    = (const float*)d_in[17];

    unsigned short* xln  = (unsigned short*)d_ws;                 // BL*1536 bf16
    unsigned short* hbuf = xln  + (size_t)BL_ * SIXH;             // BL*1024 bf16
    unsigned short* evb  = hbuf + (size_t)BL_ * FOURH;            // BL*256  bf16
    unsigned short* W1T  = evb  + (size_t)BL_ * H_;               // 1024*1536 bf16
    unsigned short* W2T  = W1T  + (size_t)FOURH * SIXH;           // 256*1024 bf16
    int* idx_map = (int*)(W2T + (size_t)H_ * FOURH);              // B*S int
    int* shiftb  = idx_map + B_ * S_;                             // B int
    float* out   = (float*)d_out;

    // weight transposes (f32 -> bf16, NxK layout for MFMA B-operand)
    transpose_bf16_kernel<<<dim3(SIXH / 32, FOURH / 32), 256, 0, stream>>>(W1, W1T, SIXH, FOURH);
    transpose_bf16_kernel<<<dim3(FOURH / 32, H_ / 32),   256, 0, stream>>>(W2, W2T, FOURH, H_);

    // embed + layernorm
    embed_ln_kernel<<<BL_, 256, 0, stream>>>(tok, ptok, atok, actok, tgap, gid,
                                             ttab, titab, gtab, gamma, beta, xln);

    // MLP
    gemm_kernel<FOURH, SIXH, 8, 0><<<(BL_ / 128) * 8, 256, 0, stream>>>(xln, W1T, b1, hbuf);
    gemm_kernel<H_, FOURH, 2, 1><<<(BL_ / 128) * 2, 256, 0, stream>>>(hbuf, W2T, b2, evb);

    // scan + inverse scatter map
    scan_scatter_kernel<<<B_, 512, 0, stream>>>(gid, lens, idx_map, shiftb);

    // final output
    out_kernel<<<dim3(S_, B_), 256, 0, stream>>>(idx_map, shiftb, evb, post, sep, out);
}

// Round 3
// 492.822 us; speedup vs baseline: 1.2660x; 1.1835x over previous
//
#include <hip/hip_runtime.h>

#define B_    128
#define L_    512
#define H_    256
#define TGB_  128
#define S_    1023
#define BL_   (B_ * L_)     // 65536
#define SIXH  1536
#define FOURH 1024

typedef __bf16 bf16_t;
typedef bf16_t bf16x8 __attribute__((ext_vector_type(8)));
typedef float  f32x4  __attribute__((ext_vector_type(4)));

__device__ __forceinline__ unsigned short f2bf(float f) {
    union { float f; unsigned u; } v; v.f = f;
    unsigned u = v.u;
    unsigned r = u + 0x7FFFu + ((u >> 16) & 1u);   // round-to-nearest-even
    return (unsigned short)(r >> 16);
}
__device__ __forceinline__ float bf2f(unsigned short s) {
    union { unsigned u; float f; } v; v.u = ((unsigned)s) << 16;
    return v.f;
}

__device__ __forceinline__ void gload_lds16(const void* g, void* l) {
    __builtin_amdgcn_global_load_lds(
        (__attribute__((address_space(1))) void*)(void*)(g),
        (__attribute__((address_space(3))) void*)(l), 16, 0, 0);
}

// ---------------------------------------------------------------------------
// K0: transpose + f32->bf16 convert:  in (R x C) f32  ->  out (C x R) bf16
// ---------------------------------------------------------------------------
__global__ __launch_bounds__(256) void transpose_bf16_kernel(
    const float* __restrict__ in, unsigned short* __restrict__ out,
    int R, int C)
{
    __shared__ float tile[32][33];
    int rb = blockIdx.x * 32, cb = blockIdx.y * 32;
    int tx = threadIdx.x & 31, ty = threadIdx.x >> 5;   // 32 x 8
    #pragma unroll
    for (int d = 0; d < 32; d += 8)
        tile[ty + d][tx] = in[(size_t)(rb + ty + d) * C + cb + tx];
    __syncthreads();
    #pragma unroll
    for (int d = 0; d < 32; d += 8)
        out[(size_t)(cb + ty + d) * R + rb + tx] = f2bf(tile[tx][ty + d]);
}

// ---------------------------------------------------------------------------
// K1: gather 6 embeddings + LayerNorm over 1536 -> x_ln bf16 (BL x 1536)
// ---------------------------------------------------------------------------
__global__ __launch_bounds__(256) void embed_ln_kernel(
    const int* __restrict__ tok,  const int* __restrict__ ptok,
    const int* __restrict__ atok, const int* __restrict__ actok,
    const int* __restrict__ tgap, const int* __restrict__ gid,
    const float* __restrict__ ttab, const float* __restrict__ titab,
    const float* __restrict__ gtab, const float* __restrict__ gamma,
    const float* __restrict__ beta, unsigned short* __restrict__ xln)
{
    int e = blockIdx.x;
    int t = threadIdx.x;
    int i0 = tok[e], i1 = ptok[e], i2 = atok[e], i3 = actok[e];
    int i4 = tgap[e]; i4 = i4 < 0 ? 0 : (i4 > TGB_ ? TGB_ : i4);
    int i5 = gid[e];
    float v0 = ttab[(size_t)i0 * H_ + t];
    float v1 = ttab[(size_t)i1 * H_ + t];
    float v2 = ttab[(size_t)i2 * H_ + t];
    float v3 = ttab[(size_t)i3 * H_ + t];
    float v4 = titab[(size_t)i4 * H_ + t];
    float v5 = gtab[(size_t)i5 * H_ + t];
    float s  = v0 + v1 + v2 + v3 + v4 + v5;
    float sq = v0*v0 + v1*v1 + v2*v2 + v3*v3 + v4*v4 + v5*v5;
    #pragma unroll
    for (int off = 32; off > 0; off >>= 1) {
        s  += __shfl_down(s,  off);
        sq += __shfl_down(sq, off);
    }
    __shared__ float red[8];
    int lane = t & 63, w = t >> 6;
    if (lane == 0) { red[w] = s; red[4 + w] = sq; }
    __syncthreads();
    float stot  = red[0] + red[1] + red[2] + red[3];
    float sqtot = red[4] + red[5] + red[6] + red[7];
    float mean = stot * (1.0f / 1536.0f);
    float var  = sqtot * (1.0f / 1536.0f) - mean * mean;
    float rstd = rsqrtf(var + 1e-5f);
    float vv[6] = { v0, v1, v2, v3, v4, v5 };
    unsigned short* orow = xln + (size_t)e * SIXH;
    #pragma unroll
    for (int k = 0; k < 6; ++k) {
        int idx = k * H_ + t;
        float y = (vv[k] - mean) * rstd * gamma[idx] + beta[idx];
        orow[idx] = f2bf(y);
    }
}

// ---------------------------------------------------------------------------
// K2: deep-pipelined bf16 MFMA GEMM, C(MxN) = epi(A(MxK) @ Bt(NxK)^T + bias)
// BM=256 x BN=128 x BK=64, 512 threads = 8 waves (4m x 2n), 16x16x32 MFMA.
// Ring-of-3 LDS slots (144 KiB dynamic), prefetch depth 2 K-tiles,
// counted s_waitcnt vmcnt(6) + raw s_barrier per K-tile (never drains to 0).
// XOR-swizzled LDS (linear gload_lds dest + inverse-swizzled global source
// + swizzled ds_read) -- verified conflict-free in round 2.
// M fixed at 65536. EPI 0: silu   EPI 1: plain bias add
// ---------------------------------------------------------------------------
template<int N, int K, int NTN, int EPI>
__global__ __launch_bounds__(512, 2) void gemm8_kernel(
    const unsigned short* __restrict__ A,
    const unsigned short* __restrict__ Bt,
    const float* __restrict__ bias,
    unsigned short* __restrict__ C)
{
    constexpr int NT    = K / 64;         // K-tiles
    constexpr int ASLOT = 256 * 64;       // shorts per A slot
    constexpr int BSLOT = 128 * 64;       // shorts per B slot
    constexpr int NBLK  = 256 * NTN;      // (M/256) * NTN
    constexpr int CHUNK = NBLK / 8;
    extern __shared__ __align__(16) unsigned short lds[];
    unsigned short* sA = lds;             // 3 * ASLOT
    unsigned short* sB = lds + 3 * ASLOT; // 3 * BSLOT

    int bid = blockIdx.x;
    int wid = (bid & 7) * CHUNK + (bid >> 3);    // XCD-bijective swizzle
    int mt  = wid / NTN;
    int m0  = mt * 256;
    int n0  = (wid - mt * NTN) * 128;

    int t = threadIdx.x;
    int w = t >> 6, l = t & 63;
    int srow = t >> 3;                       // 0..63
    int scg  = (t & 7) ^ (srow & 7);         // inverse-swizzled source chunk
    const unsigned short* Ag = A  + (size_t)(m0 + srow) * K + scg * 8;
    const unsigned short* Bg = Bt + (size_t)(n0 + srow) * K + scg * 8;
    unsigned short* stA = sA + w * 512;      // wave-uniform staging base
    unsigned short* stB = sB + w * 512;

    int r16 = l & 15, q = l >> 4;
    int wm = w >> 1, wn = w & 1;             // 4m x 2n wave grid
    int xr = r16 & 7;
    const int aoff = (wm * 64 + r16) * 64;
    const int boff = (wn * 64 + r16) * 64;
    const int c0 = ((0 + q) ^ xr) * 8;       // kk=0 swizzled chunk byte/2 off
    const int c1 = ((4 + q) ^ xr) * 8;       // kk=1

    f32x4 acc[4][4];
    #pragma unroll
    for (int i = 0; i < 4; ++i)
        #pragma unroll
        for (int j = 0; j < 4; ++j) acc[i][j] = (f32x4)0.0f;

    // prologue: stage kt=0 -> slot0, kt=1 -> slot1 (6 loads each)
    #pragma unroll
    for (int j = 0; j < 4; ++j) gload_lds16(Ag + (size_t)j * 64 * K, stA + j * 4096);
    #pragma unroll
    for (int j = 0; j < 2; ++j) gload_lds16(Bg + (size_t)j * 64 * K, stB + j * 4096);
    #pragma unroll
    for (int j = 0; j < 4; ++j) gload_lds16(Ag + (size_t)j * 64 * K + 64, stA + ASLOT + j * 4096);
    #pragma unroll
    for (int j = 0; j < 2; ++j) gload_lds16(Bg + (size_t)j * 64 * K + 64, stB + BSLOT + j * 4096);
    asm volatile("s_waitcnt vmcnt(6)\ns_barrier" ::: "memory");

    int s = 0;
    for (int kt = 0; kt < NT; ++kt) {
        const unsigned short* sAs = sA + s * ASLOT;
        const unsigned short* sBs = sB + s * BSLOT;
        int spf = s + 2; if (spf >= 3) spf -= 3;      // slot for kt+2
        const size_t gofs = (size_t)(kt + 2) * 64;
        unsigned short* pA = stA + spf * ASLOT;
        unsigned short* pB = stB + spf * BSLOT;

        bf16x8 af[4][2];
        #pragma unroll
        for (int mi = 0; mi < 4; ++mi) {
            af[mi][0] = *(const bf16x8*)(sAs + aoff + mi * 1024 + c0);
            af[mi][1] = *(const bf16x8*)(sAs + aoff + mi * 1024 + c1);
        }
        #pragma unroll
        for (int ni = 0; ni < 4; ++ni) {
            bf16x8 b0 = *(const bf16x8*)(sBs + boff + ni * 1024 + c0);
            bf16x8 b1 = *(const bf16x8*)(sBs + boff + ni * 1024 + c1);
            if (kt + 2 < NT) {      // interleave next-next tile staging
                if (ni == 0) {
                    gload_lds16(Ag + gofs,                    pA);
                    gload_lds16(Ag + (size_t) 64 * K + gofs,  pA + 4096);
                } else if (ni == 1) {
                    gload_lds16(Ag + (size_t)128 * K + gofs,  pA + 8192);
                    gload_lds16(Ag + (size_t)192 * K + gofs,  pA + 12288);
                } else if (ni == 2) {
                    gload_lds16(Bg + gofs,                    pB);
                } else {
                    gload_lds16(Bg + (size_t) 64 * K + gofs,  pB + 4096);
                }
            }
            __builtin_amdgcn_s_setprio(1);
            #pragma unroll
            for (int mi = 0; mi < 4; ++mi) {
                acc[mi][ni] = __builtin_amdgcn_mfma_f32_16x16x32_bf16(af[mi][0], b0, acc[mi][ni], 0, 0, 0);
                acc[mi][ni] = __builtin_amdgcn_mfma_f32_16x16x32_bf16(af[mi][1], b1, acc[mi][ni], 0, 0, 0);
            }
            __builtin_amdgcn_s_setprio(0);
        }
        if (kt + 2 < NT)      asm volatile("s_waitcnt vmcnt(6)\ns_barrier" ::: "memory");
        else if (kt + 1 < NT) asm volatile("s_waitcnt vmcnt(0)\ns_barrier" ::: "memory");
        s = (s == 2) ? 0 : s + 1;
    }

    #pragma unroll
    for (int mi = 0; mi < 4; ++mi) {
        #pragma unroll
        for (int ni = 0; ni < 4; ++ni) {
            int col = n0 + wn * 64 + ni * 16 + r16;
            float bv = bias[col];
            #pragma unroll
            for (int j = 0; j < 4; ++j) {
                int row = m0 + wm * 64 + mi * 16 + q * 4 + j;
                float v = acc[mi][ni][j] + bv;
                if (EPI == 0) v = v / (1.0f + __expf(-v));   // silu
                C[(size_t)row * N + col] = f2bf(v);
            }
        }
    }
}

// ---------------------------------------------------------------------------
// K3: per-batch boundary + exclusive cumsum + inverse index map
// ---------------------------------------------------------------------------
__global__ __launch_bounds__(512) void scan_scatter_kernel(
    const int* __restrict__ gid, const int* __restrict__ lengths,
    int* __restrict__ idx_map, int* __restrict__ shiftb)
{
    int b = blockIdx.x, i = threadIdx.x;
    int len = lengths[b];
    int g  = gid[b * L_ + i];
    int gn = (i < L_ - 1) ? gid[b * L_ + i + 1] : g;
    int bnd = (i < len - 1 && g != gn) ? 1 : 0;
    __shared__ int sc[512];
    sc[i] = bnd;
    __syncthreads();
    for (int off = 1; off < 512; off <<= 1) {
        int v = (i >= off) ? sc[i - off] : 0;
        __syncthreads();
        sc[i] += v;
        __syncthreads();
    }
    int incl  = sc[i];
    int total = sc[511];
    int ex = incl - bnd;
    int M = len + total;
    int shift = S_ - M;          // always >= 0
    for (int s = i; s < S_; s += 512) idx_map[b * S_ + s] = -1;
    __syncthreads();
    if (i < len) {
        int p = shift + i + ex;
        idx_map[b * S_ + p] = i;
        if (bnd) idx_map[b * S_ + p + 1] = -2;
    }
    if (i == 0) shiftb[b] = shift;
}

// ---------------------------------------------------------------------------
// K4: final fill: merged[b][s][:] and mask[b][s]
// ---------------------------------------------------------------------------
__global__ __launch_bounds__(256) void out_kernel(
    const int* __restrict__ idx_map, const int* __restrict__ shiftb,
    const unsigned short* __restrict__ event,
    const float* __restrict__ pos_table, const float* __restrict__ sep,
    float* __restrict__ out)
{
    int s = blockIdx.x, b = blockIdx.y, t = threadIdx.x;
    int shift = shiftb[b];
    float val = 0.0f;
    if (s >= shift) {
        int idx = idx_map[b * S_ + s];
        float add = 0.0f;
        if (idx >= 0)       add = bf2f(event[((size_t)b * L_ + idx) * H_ + t]);
        else if (idx == -2) add = sep[t];
        val = pos_table[(size_t)s * H_ + t] + add;
    }
    out[((size_t)b * S_ + s) * H_ + t] = val;
    if (t == 0)
        out[(size_t)B_ * S_ * H_ + (size_t)b * S_ + s] = (s >= shift) ? 1.0f : 0.0f;
}

// ---------------------------------------------------------------------------
extern "C" void kernel_launch(void* const* d_in, const int* in_sizes, int n_in,
                              void* d_out, int out_size, void* d_ws, size_t ws_size,
                              hipStream_t stream)
{
    const int*   tok   = (const int*)d_in[0];
    const int*   ptok  = (const int*)d_in[1];
    const int*   atok  = (const int*)d_in[2];
    const int*   actok = (const int*)d_in[3];
    const int*   tgap  = (const int*)d_in[4];
    const int*   gid   = (const int*)d_in[5];
    const int*   lens  = (const int*)d_in[6];
    const float* ttab  = (const float*)d_in[7];
    const float* titab = (const float*)d_in[8];
    const float* gtab  = (const float*)d_in[9];
    const float* post  = (const float*)d_in[10];
    const float* sep   = (const float*)d_in[11];
    const float* gamma = (const float*)d_in[12];
    const float* beta  = (const float*)d_in[13];
    const float* W1    = (const float*)d_in[14];
    const float* b1    = (const float*)d_in[15];
    const float* W2    = (const float*)d_in[16];
    const float* b2    = (const float*)d_in[17];

    unsigned short* xln  = (unsigned short*)d_ws;                 // BL*1536 bf16
    unsigned short* hbuf = xln  + (size_t)BL_ * SIXH;             // BL*1024 bf16
    unsigned short* evb  = hbuf + (size_t)BL_ * FOURH;            // BL*256  bf16
    unsigned short* W1T  = evb  + (size_t)BL_ * H_;               // 1024*1536 bf16
    unsigned short* W2T  = W1T  + (size_t)FOURH * SIXH;           // 256*1024 bf16
    int* idx_map = (int*)(W2T + (size_t)H_ * FOURH);              // B*S int
    int* shiftb  = idx_map + B_ * S_;                             // B int
    float* out   = (float*)d_out;

    constexpr int LDS_BYTES = 3 * (256 * 64 + 128 * 64) * 2;      // 147456
    (void)hipFuncSetAttribute((const void*)&gemm8_kernel<FOURH, SIXH, 8, 0>,
                              hipFuncAttributeMaxDynamicSharedMemorySize, LDS_BYTES);
    (void)hipFuncSetAttribute((const void*)&gemm8_kernel<H_, FOURH, 2, 1>,
                              hipFuncAttributeMaxDynamicSharedMemorySize, LDS_BYTES);

    // weight transposes (f32 -> bf16, NxK layout for MFMA B-operand)
    transpose_bf16_kernel<<<dim3(SIXH / 32, FOURH / 32), 256, 0, stream>>>(W1, W1T, SIXH, FOURH);
    transpose_bf16_kernel<<<dim3(FOURH / 32, H_ / 32),   256, 0, stream>>>(W2, W2T, FOURH, H_);

    // embed + layernorm
    embed_ln_kernel<<<BL_, 256, 0, stream>>>(tok, ptok, atok, actok, tgap, gid,
                                             ttab, titab, gtab, gamma, beta, xln);

    // MLP (deep-pipelined GEMMs)
    gemm8_kernel<FOURH, SIXH, 8, 0><<<(BL_ / 256) * 8, 512, LDS_BYTES, stream>>>(xln, W1T, b1, hbuf);
    gemm8_kernel<H_, FOURH, 2, 1><<<(BL_ / 256) * 2, 512, LDS_BYTES, stream>>>(hbuf, W2T, b2, evb);

    // scan + inverse scatter map
    scan_scatter_kernel<<<B_, 512, 0, stream>>>(gid, lens, idx_map, shiftb);

    // final output
    out_kernel<<<dim3(S_, B_), 256, 0, stream>>>(idx_map, shiftb, evb, post, sep, out);
}

// Round 4
// 457.283 us; speedup vs baseline: 1.3644x; 1.0777x over previous
//
#include <hip/hip_runtime.h>

#define B_    128
#define L_    512
#define H_    256
#define TGB_  128
#define S_    1023
#define BL_   (B_ * L_)     // 65536
#define SIXH  1536
#define FOURH 1024

typedef __bf16 bf16_t;
typedef bf16_t bf16x8 __attribute__((ext_vector_type(8)));
typedef float  f32x4  __attribute__((ext_vector_type(4)));

template<int P> struct IC { static constexpr int v = P; };

__device__ __forceinline__ unsigned short f2bf(float f) {
    union { float f; unsigned u; } v; v.f = f;
    unsigned u = v.u;
    unsigned r = u + 0x7FFFu + ((u >> 16) & 1u);   // round-to-nearest-even
    return (unsigned short)(r >> 16);
}
__device__ __forceinline__ float bf2f(unsigned short s) {
    union { unsigned u; float f; } v; v.u = ((unsigned)s) << 16;
    return v.f;
}

__device__ __forceinline__ void gload_lds16(const void* g, void* l) {
    __builtin_amdgcn_global_load_lds(
        (__attribute__((address_space(1))) void*)(void*)(g),
        (__attribute__((address_space(3))) void*)(l), 16, 0, 0);
}

// ---------------------------------------------------------------------------
// K0: transpose + f32->bf16 convert:  in (R x C) f32  ->  out (C x R) bf16
// ---------------------------------------------------------------------------
__global__ __launch_bounds__(256) void transpose_bf16_kernel(
    const float* __restrict__ in, unsigned short* __restrict__ out,
    int R, int C)
{
    __shared__ float tile[32][33];
    int rb = blockIdx.x * 32, cb = blockIdx.y * 32;
    int tx = threadIdx.x & 31, ty = threadIdx.x >> 5;   // 32 x 8
    #pragma unroll
    for (int d = 0; d < 32; d += 8)
        tile[ty + d][tx] = in[(size_t)(rb + ty + d) * C + cb + tx];
    __syncthreads();
    #pragma unroll
    for (int d = 0; d < 32; d += 8)
        out[(size_t)(cb + ty + d) * R + rb + tx] = f2bf(tile[tx][ty + d]);
}

// ---------------------------------------------------------------------------
// K1: gather 6 embeddings + LayerNorm over 1536 -> x_ln bf16 (BL x 1536)
// ---------------------------------------------------------------------------
__global__ __launch_bounds__(256) void embed_ln_kernel(
    const int* __restrict__ tok,  const int* __restrict__ ptok,
    const int* __restrict__ atok, const int* __restrict__ actok,
    const int* __restrict__ tgap, const int* __restrict__ gid,
    const float* __restrict__ ttab, const float* __restrict__ titab,
    const float* __restrict__ gtab, const float* __restrict__ gamma,
    const float* __restrict__ beta, unsigned short* __restrict__ xln)
{
    int e = blockIdx.x;
    int t = threadIdx.x;
    int i0 = tok[e], i1 = ptok[e], i2 = atok[e], i3 = actok[e];
    int i4 = tgap[e]; i4 = i4 < 0 ? 0 : (i4 > TGB_ ? TGB_ : i4);
    int i5 = gid[e];
    float v0 = ttab[(size_t)i0 * H_ + t];
    float v1 = ttab[(size_t)i1 * H_ + t];
    float v2 = ttab[(size_t)i2 * H_ + t];
    float v3 = ttab[(size_t)i3 * H_ + t];
    float v4 = titab[(size_t)i4 * H_ + t];
    float v5 = gtab[(size_t)i5 * H_ + t];
    float s  = v0 + v1 + v2 + v3 + v4 + v5;
    float sq = v0*v0 + v1*v1 + v2*v2 + v3*v3 + v4*v4 + v5*v5;
    #pragma unroll
    for (int off = 32; off > 0; off >>= 1) {
        s  += __shfl_down(s,  off);
        sq += __shfl_down(sq, off);
    }
    __shared__ float red[8];
    int lane = t & 63, w = t >> 6;
    if (lane == 0) { red[w] = s; red[4 + w] = sq; }
    __syncthreads();
    float stot  = red[0] + red[1] + red[2] + red[3];
    float sqtot = red[4] + red[5] + red[6] + red[7];
    float mean = stot * (1.0f / 1536.0f);
    float var  = sqtot * (1.0f / 1536.0f) - mean * mean;
    float rstd = rsqrtf(var + 1e-5f);
    float vv[6] = { v0, v1, v2, v3, v4, v5 };
    unsigned short* orow = xln + (size_t)e * SIXH;
    #pragma unroll
    for (int k = 0; k < 6; ++k) {
        int idx = k * H_ + t;
        float y = (vv[k] - mean) * rstd * gamma[idx] + beta[idx];
        orow[idx] = f2bf(y);
    }
}

// ---------------------------------------------------------------------------
// K2: 8-phase 256x256 bf16 MFMA GEMM (m201-template port).
// C(MxN) = epi(A(MxK) @ Bt(NxK)^T + bias), M = 65536.
// 512 threads = 8 waves (2m x 4n), per-wave C = 128x64, 16x16x32 MFMA.
// LDS 128 KiB: 2 bufs (kt parity) x { A[2 kh][256r][32c], B[...] }.
// Staging: 1 K-half unit (2 gload_lds/thread) per phase, 6-phase lead;
// counted s_waitcnt vmcnt(4) at phases 3 and 7 only (never drains mid-loop).
// XOR swizzle f = ql ^ ((row>>1)&3) applied on pre-swizzled global source
// and on ds_read (both-sides rule).
// EPI 0: silu   EPI 1: plain bias add
// ---------------------------------------------------------------------------
template<int N, int K, int NTN, int EPI>
__global__ __launch_bounds__(512, 2) void gemm256_kernel(
    const unsigned short* __restrict__ A,
    const unsigned short* __restrict__ Bt,
    const float* __restrict__ bias,
    unsigned short* __restrict__ C)
{
    constexpr int NT = K / 64;        // K-tiles
    constexpr int IT = NT / 2;        // 2 K-tiles per iteration
    constexpr int NBLK = 256 * NTN;   // (M/256) * NTN
    constexpr int CHUNK = NBLK / 8;
    extern __shared__ __align__(16) unsigned short lds[];   // 65536 shorts

    const int bid = blockIdx.x;
    const int wid = (bid & 7) * CHUNK + (bid >> 3);   // XCD-bijective swizzle
    const int mt  = wid / NTN;
    const int m0  = mt * 256;
    const int n0  = (wid - mt * NTN) * 256;

    const int t = threadIdx.x;
    const int w = t >> 6, l = t & 63;
    const int wm = w >> 2, wn = w & 3;
    const int r16 = l & 15, ql = l >> 4;

    // --- staging (thread-fixed): row (t>>2) in each 128-row round, chunk t&3
    const int sg = (t & 3) ^ ((t >> 3) & 3);          // inverse-swizzled source group
    const unsigned short* Ast = A  + (size_t)(m0 + (t >> 2)) * K + sg * 8;
    const unsigned short* Bst = Bt + (size_t)(n0 + (t >> 2)) * K + sg * 8;
    const int stbase = w * 512;                        // wave-uniform LDS base (shorts)

    // --- fragment read offsets (shorts); add kk*8192 + buf*32768 per phase
    const int fr   = (ql ^ ((r16 >> 1) & 3)) * 8;
    const int arow = (wm * 128 + r16) * 32 + fr;       // + mi*512
    const int brow = 16384 + (wn * 64 + r16) * 32 + fr; // + ni*512

    f32x4 acc[8][4];
    #pragma unroll
    for (int i = 0; i < 8; ++i)
        #pragma unroll
        for (int j = 0; j < 4; ++j) acc[i][j] = (f32x4)0.0f;

    // stage one unit of the global stream: unit u -> kt=u>>2, isB=u&1, kh=(u>>1)&1
    auto STAGE_UNIT = [&](int u) {
        int kt = u >> 2;
        if (kt >= NT) return;
        int isB = u & 1, kh = (u >> 1) & 1, buf = kt & 1;
        const unsigned short* src = isB ? Bst : Ast;
        unsigned short* d0 = lds + buf * 32768 + isB * 16384 + kh * 8192 + stbase;
        size_t gc = (size_t)kt * 64 + kh * 32;
        gload_lds16(src + gc,                    d0);          // rows 0..127
        gload_lds16(src + (size_t)128 * K + gc,  d0 + 4096);   // rows 128..255
    };

    // prologue: units 0..5 (kt0 full + kt1 kh0), need units 0..3 before phase 0
    for (int u = 0; u < 6; ++u) STAGE_UNIT(u);
    asm volatile("s_waitcnt vmcnt(4)\ns_barrier" ::: "memory");

    bf16x8 aq[4], bq[4];

    auto phase = [&](auto pc, int ubase, bool last) {
        constexpr int P  = decltype(pc)::v;
        constexpr int KTP = P >> 2, Q = P & 3, KK = Q >> 1, MH = Q & 1;
        const unsigned short* bp = lds + KTP * 32768 + KK * 8192;
        if (Q == 0 || Q == 2) {     // new kk: load all 4 B frags
            bq[0] = *(const bf16x8*)(bp + brow);
            bq[1] = *(const bf16x8*)(bp + brow + 512);
            bq[2] = *(const bf16x8*)(bp + brow + 1024);
            bq[3] = *(const bf16x8*)(bp + brow + 1536);
        }
        aq[0] = *(const bf16x8*)(bp + arow + MH * 2048);
        aq[1] = *(const bf16x8*)(bp + arow + MH * 2048 + 512);
        aq[2] = *(const bf16x8*)(bp + arow + MH * 2048 + 1024);
        aq[3] = *(const bf16x8*)(bp + arow + MH * 2048 + 1536);
        STAGE_UNIT(ubase + P);
        asm volatile("s_barrier" ::: "memory");
        asm volatile("s_waitcnt lgkmcnt(0)" ::: "memory");
        __builtin_amdgcn_s_setprio(1);
        #pragma unroll
        for (int mm = 0; mm < 4; ++mm)
            #pragma unroll
            for (int nn = 0; nn < 4; ++nn)
                acc[MH * 4 + mm][nn] = __builtin_amdgcn_mfma_f32_16x16x32_bf16(
                    aq[mm], bq[nn], acc[MH * 4 + mm][nn], 0, 0, 0);
        __builtin_amdgcn_s_setprio(0);
        if (P == 3) {
            if (last) asm volatile("s_waitcnt vmcnt(0)\ns_barrier" ::: "memory");
            else      asm volatile("s_waitcnt vmcnt(4)\ns_barrier" ::: "memory");
        } else if (P == 7) {
            if (!last) asm volatile("s_waitcnt vmcnt(4)\ns_barrier" ::: "memory");
        } else {
            asm volatile("s_barrier" ::: "memory");
        }
    };

    for (int it = 0; it < IT; ++it) {
        const bool last = (it == IT - 1);
        const int ubase = 8 * it + 6;
        phase(IC<0>{}, ubase, last);
        phase(IC<1>{}, ubase, last);
        phase(IC<2>{}, ubase, last);
        phase(IC<3>{}, ubase, last);
        phase(IC<4>{}, ubase, last);
        phase(IC<5>{}, ubase, last);
        phase(IC<6>{}, ubase, last);
        phase(IC<7>{}, ubase, last);
    }

    // epilogue
    #pragma unroll
    for (int mi = 0; mi < 8; ++mi) {
        #pragma unroll
        for (int ni = 0; ni < 4; ++ni) {
            int col = n0 + wn * 64 + ni * 16 + r16;
            float bv = bias[col];
            #pragma unroll
            for (int j = 0; j < 4; ++j) {
                int row = m0 + wm * 128 + mi * 16 + ql * 4 + j;
                float v = acc[mi][ni][j] + bv;
                if (EPI == 0) v = v / (1.0f + __expf(-v));   // silu
                C[(size_t)row * N + col] = f2bf(v);
            }
        }
    }
}

// ---------------------------------------------------------------------------
// K3: per-batch boundary + exclusive cumsum + inverse index map
// ---------------------------------------------------------------------------
__global__ __launch_bounds__(512) void scan_scatter_kernel(
    const int* __restrict__ gid, const int* __restrict__ lengths,
    int* __restrict__ idx_map, int* __restrict__ shiftb)
{
    int b = blockIdx.x, i = threadIdx.x;
    int len = lengths[b];
    int g  = gid[b * L_ + i];
    int gn = (i < L_ - 1) ? gid[b * L_ + i + 1] : g;
    int bnd = (i < len - 1 && g != gn) ? 1 : 0;
    __shared__ int sc[512];
    sc[i] = bnd;
    __syncthreads();
    for (int off = 1; off < 512; off <<= 1) {
        int v = (i >= off) ? sc[i - off] : 0;
        __syncthreads();
        sc[i] += v;
        __syncthreads();
    }
    int incl  = sc[i];
    int total = sc[511];
    int ex = incl - bnd;
    int M = len + total;
    int shift = S_ - M;          // always >= 0
    for (int s = i; s < S_; s += 512) idx_map[b * S_ + s] = -1;
    __syncthreads();
    if (i < len) {
        int p = shift + i + ex;
        idx_map[b * S_ + p] = i;
        if (bnd) idx_map[b * S_ + p + 1] = -2;
    }
    if (i == 0) shiftb[b] = shift;
}

// ---------------------------------------------------------------------------
// K4: final fill: merged[b][s][:] and mask[b][s]
// ---------------------------------------------------------------------------
__global__ __launch_bounds__(256) void out_kernel(
    const int* __restrict__ idx_map, const int* __restrict__ shiftb,
    const unsigned short* __restrict__ event,
    const float* __restrict__ pos_table, const float* __restrict__ sep,
    float* __restrict__ out)
{
    int s = blockIdx.x, b = blockIdx.y, t = threadIdx.x;
    int shift = shiftb[b];
    float val = 0.0f;
    if (s >= shift) {
        int idx = idx_map[b * S_ + s];
        float add = 0.0f;
        if (idx >= 0)       add = bf2f(event[((size_t)b * L_ + idx) * H_ + t]);
        else if (idx == -2) add = sep[t];
        val = pos_table[(size_t)s * H_ + t] + add;
    }
    out[((size_t)b * S_ + s) * H_ + t] = val;
    if (t == 0)
        out[(size_t)B_ * S_ * H_ + (size_t)b * S_ + s] = (s >= shift) ? 1.0f : 0.0f;
}

// ---------------------------------------------------------------------------
extern "C" void kernel_launch(void* const* d_in, const int* in_sizes, int n_in,
                              void* d_out, int out_size, void* d_ws, size_t ws_size,
                              hipStream_t stream)
{
    const int*   tok   = (const int*)d_in[0];
    const int*   ptok  = (const int*)d_in[1];
    const int*   atok  = (const int*)d_in[2];
    const int*   actok = (const int*)d_in[3];
    const int*   tgap  = (const int*)d_in[4];
    const int*   gid   = (const int*)d_in[5];
    const int*   lens  = (const int*)d_in[6];
    const float* ttab  = (const float*)d_in[7];
    const float* titab = (const float*)d_in[8];
    const float* gtab  = (const float*)d_in[9];
    const float* post  = (const float*)d_in[10];
    const float* sep   = (const float*)d_in[11];
    const float* gamma = (const float*)d_in[12];
    const float* beta  = (const float*)d_in[13];
    const float* W1    = (const float*)d_in[14];
    const float* b1    = (const float*)d_in[15];
    const float* W2    = (const float*)d_in[16];
    const float* b2    = (const float*)d_in[17];

    unsigned short* xln  = (unsigned short*)d_ws;                 // BL*1536 bf16
    unsigned short* hbuf = xln  + (size_t)BL_ * SIXH;             // BL*1024 bf16
    unsigned short* evb  = hbuf + (size_t)BL_ * FOURH;            // BL*256  bf16
    unsigned short* W1T  = evb  + (size_t)BL_ * H_;               // 1024*1536 bf16
    unsigned short* W2T  = W1T  + (size_t)FOURH * SIXH;           // 256*1024 bf16
    int* idx_map = (int*)(W2T + (size_t)H_ * FOURH);              // B*S int
    int* shiftb  = idx_map + B_ * S_;                             // B int
    float* out   = (float*)d_out;

    constexpr int LDS_BYTES = 2 * 32768 * 2;                      // 131072
    (void)hipFuncSetAttribute((const void*)&gemm256_kernel<FOURH, SIXH, 4, 0>,
                              hipFuncAttributeMaxDynamicSharedMemorySize, LDS_BYTES);
    (void)hipFuncSetAttribute((const void*)&gemm256_kernel<H_, FOURH, 1, 1>,
                              hipFuncAttributeMaxDynamicSharedMemorySize, LDS_BYTES);

    // weight transposes (f32 -> bf16, NxK layout for MFMA B-operand)
    transpose_bf16_kernel<<<dim3(SIXH / 32, FOURH / 32), 256, 0, stream>>>(W1, W1T, SIXH, FOURH);
    transpose_bf16_kernel<<<dim3(FOURH / 32, H_ / 32),   256, 0, stream>>>(W2, W2T, FOURH, H_);

    // embed + layernorm
    embed_ln_kernel<<<BL_, 256, 0, stream>>>(tok, ptok, atok, actok, tgap, gid,
                                             ttab, titab, gtab, gamma, beta, xln);

    // MLP (8-phase 256^2 GEMMs)
    gemm256_kernel<FOURH, SIXH, 4, 0><<<(BL_ / 256) * 4, 512, LDS_BYTES, stream>>>(xln, W1T, b1, hbuf);
    gemm256_kernel<H_, FOURH, 1, 1><<<(BL_ / 256) * 1, 512, LDS_BYTES, stream>>>(hbuf, W2T, b2, evb);

    // scan + inverse scatter map
    scan_scatter_kernel<<<B_, 512, 0, stream>>>(gid, lens, idx_map, shiftb);

    // final output
    out_kernel<<<dim3(S_, B_), 256, 0, stream>>>(idx_map, shiftb, evb, post, sep, out);
}